// Round 5
// baseline (204.247 us; speedup 1.0000x reference)
//
#include <hip/hip_runtime.h>
#include <math.h>

#define HW 4096

typedef __attribute__((ext_vector_type(8))) short short8;
typedef __attribute__((ext_vector_type(4))) float f32x4;

static __device__ inline ushort f2bf(float f) {
    uint u = __builtin_bit_cast(uint, f);
    return (ushort)((u + 0x7fffu + ((u >> 16) & 1u)) >> 16);
}
static __device__ inline float lof(uint u) { return __builtin_bit_cast(float, u << 16); }
static __device__ inline float hif(uint u) { return __builtin_bit_cast(float, u & 0xffff0000u); }

// ---------------- k0: x [b][c][h][w] f32 -> x_t [b][h][w][c] bf16 (c-half blocks) ----------------
__global__ __launch_bounds__(256) void k0_xt(const float* __restrict__ x, ushort* __restrict__ xt)
{
    const int blk = blockIdx.x;              // b*128 + h*2 + ch
    const int b = blk >> 7, h = (blk & 127) >> 1, ch = blk & 1;
    __shared__ ushort tile[64 * 130];
    const float* xb = x + ((size_t)(b * 256 + ch * 128)) * HW + h * 64;
    const int t = threadIdx.x;
    for (int e = t; e < 8192; e += 256) {
        const int c = e >> 6, j = e & 63;
        tile[j * 130 + c] = f2bf(xb[c * HW + j]);
    }
    __syncthreads();
    for (int e = t; e < 4096; e += 256) {
        const int j = e >> 6, q = e & 63;
        uint* xo = (uint*)(xt + ((size_t)b * HW + h * 64 + j) * 256 + ch * 128);
        xo[q] = *(const uint*)&tile[j * 130 + 2 * q];
    }
}

// ---------------- k0w: weights prep (merged) ----------------
// bid<256: w_dcn [d][c][3][3] -> wT [k][d][c] bf16 ; bid>=256: w_off -> wA [tap][oc_pad32][c]
__global__ __launch_bounds__(256) void k0_w(const float* __restrict__ w_dcn,
    const float* __restrict__ w_off, ushort* __restrict__ wT, ushort* __restrict__ wA)
{
    const int bid = blockIdx.x;
    const int t = threadIdx.x;
    if (bid < 256) {
        const int d = bid;
        __shared__ float wl[2304];
        for (int i = t; i < 2304; i += 256) wl[i] = w_dcn[d * 2304 + i];
        __syncthreads();
        for (int i = t; i < 2304; i += 256) {
            const int k = i >> 8, c = i & 255;
            wT[k * 65536 + d * 256 + c] = f2bf(wl[c * 9 + k]);
        }
    } else {
        const int e = (bid - 256) * 256 + t;     // 73728 = 9*32*256
        const int k = e >> 13, r = e & 8191;
        const int oc = r >> 8, c = r & 255;
        wA[e] = f2bf(oc < 27 ? w_off[(oc * 256 + c) * 9 + k] : 0.f);
    }
}

// ---------------- k1: offset conv MFMA; block=(b,h,whalf); 8 waves = 2 wgrp x 4 cquarter ----------------
__global__ __launch_bounds__(512) void k1_mfma(const ushort* __restrict__ xt,
    const ushort* __restrict__ wA, const float* __restrict__ b_off,
    float* __restrict__ offs, float* __restrict__ mk)
{
    const int bid = blockIdx.x;
    const int b = bid >> 7, rr_ = bid & 127, h = rr_ >> 1, wh = rr_ & 1;
    const int t = threadIdx.x;
    const int lane = t & 63, wv = t >> 6;
    const int wq = wv & 1, cq = wv >> 1;
    const int n = lane & 15, kq = lane >> 4;
    __shared__ float red[2][3][64][8];

    f32x4 acc0 = {0.f, 0.f, 0.f, 0.f}, acc1 = {0.f, 0.f, 0.f, 0.f};
    const ushort* xb = xt + ((size_t)b * HW) * 256;
    const int wcol = wh * 32 + wq * 16 + n;
    const int cb = cq * 64 + kq * 8;

#pragma unroll
    for (int k = 0; k < 9; ++k) {
        const int i = k / 3, j = k % 3;
        const int hh = h + 2 * (i - 1);
        const int ww = wcol + 2 * (j - 1);
        const bool ok = ((unsigned)hh < 64u) && ((unsigned)ww < 64u);
        const int hc = min(max(hh, 0), 63), wc = min(max(ww, 0), 63);
        const ushort* xrow = xb + (hc * 64 + wc) * 256 + cb;
        const ushort* wr0 = wA + (k * 32 + n) * 256 + cb;
#pragma unroll
        for (int c0 = 0; c0 < 64; c0 += 32) {
            short8 bv = *(const short8*)(xrow + c0);
            if (!ok) bv = (short8){0, 0, 0, 0, 0, 0, 0, 0};
            const short8 a0 = *(const short8*)(wr0 + c0);
            const short8 a1 = *(const short8*)(wr0 + 16 * 256 + c0);
            acc0 = __builtin_amdgcn_mfma_f32_16x16x32_bf16(a0, bv, acc0, 0, 0, 0);
            acc1 = __builtin_amdgcn_mfma_f32_16x16x32_bf16(a1, bv, acc1, 0, 0, 0);
        }
    }

    if (cq > 0) {
#pragma unroll
        for (int r = 0; r < 4; ++r) {
            red[wq][cq - 1][lane][r]     = acc0[r];
            red[wq][cq - 1][lane][4 + r] = acc1[r];
        }
    }
    __syncthreads();
    if (cq == 0) {
#pragma unroll
        for (int p = 0; p < 3; ++p)
#pragma unroll
            for (int r = 0; r < 4; ++r) {
                acc0[r] += red[wq][p][lane][r];
                acc1[r] += red[wq][p][lane][4 + r];
            }
        const int hw = h * 64 + wcol;
#pragma unroll
        for (int r = 0; r < 4; ++r) {
            {
                const int oc = kq * 4 + r;
                float v = acc0[r] + b_off[oc];
                v = fminf(fmaxf(v, -64.f), 64.f);
                offs[(b * 18 + oc) * HW + hw] = v;
            }
            {
                const int oc = 16 + kq * 4 + r;
                const float v = acc1[r] + b_off[min(oc, 26)];
                if (oc < 18) {
                    offs[(b * 18 + oc) * HW + hw] = fminf(fmaxf(v, -64.f), 64.f);
                } else if (oc < 27) {
                    mk[(b * 9 + (oc - 18)) * HW + hw] = 1.f / (1.f + expf(-v));
                }
            }
        }
    }
}

// ---------------- k2: fused sampling + MFMA GEMM ----------------
// block = (b, h, w-half); 256 threads = 4 waves; wave wv = d rows [wv*64, wv*64+64), 32 w cols.
// Per tap: stage samp[32w][256c] bf16 (XOR-swizzled granules), dbuf, 1 barrier/tap.
__global__ __launch_bounds__(256) void k2_dcn(const ushort* __restrict__ xt, const ushort* __restrict__ wT,
    const float* __restrict__ offs, const float* __restrict__ mk, float* __restrict__ out)
{
    const int bid = blockIdx.x;
    const int wg = (bid & 7) * 64 + (bid >> 3);      // XCD-bijective swizzle (512 = 8*64)
    const int b = wg >> 7, h = (wg & 127) >> 1, wh = wg & 1;
    const int t = threadIdx.x;
    const int lane = t & 63, wv = t >> 6;
    const int n0 = lane & 15, kq = lane >> 4;
    const int d0 = wv * 64;

    __shared__ __align__(16) ushort S[2][8192];      // 2 x 32w x 256c bf16 = 32 KB
    __shared__ int4   cOff[288];
    __shared__ float4 cWgt[288];

    // meta: 9 taps x 32 w
    for (int e = t; e < 288; e += 256) {
        const int k = e >> 5, sl = e & 31, w = wh * 32 + sl;
        const float dy = offs[((size_t)b * 18 + 2 * k) * HW + h * 64 + w];
        const float dx = offs[((size_t)b * 18 + 2 * k + 1) * HW + h * 64 + w];
        const float mval = mk[((size_t)b * 9 + k) * HW + h * 64 + w];
        const float py = (float)(h - 1 + k / 3) + dy;
        const float px = (float)(w - 1 + k % 3) + dx;
        const float y0f = floorf(py), x0f = floorf(px);
        const float wy = py - y0f, wx = px - x0f;
        const int y0 = (int)y0f, x0 = (int)x0f;
        float w00 = (1.f - wy) * (1.f - wx) * mval, w01 = (1.f - wy) * wx * mval;
        float w10 = wy * (1.f - wx) * mval,         w11 = wy * wx * mval;
        const bool vy0 = (unsigned)y0 < 64u, vy1 = (unsigned)(y0 + 1) < 64u;
        const bool vx0 = (unsigned)x0 < 64u, vx1 = (unsigned)(x0 + 1) < 64u;
        if (!(vy0 && vx0)) w00 = 0.f;
        if (!(vy0 && vx1)) w01 = 0.f;
        if (!(vy1 && vx0)) w10 = 0.f;
        if (!(vy1 && vx1)) w11 = 0.f;
        const int y0c = min(max(y0, 0), 63), y1c = min(max(y0 + 1, 0), 63);
        const int x0c = min(max(x0, 0), 63), x1c = min(max(x0 + 1, 0), 63);
        cOff[e] = make_int4((y0c * 64 + x0c) * 512, (y0c * 64 + x1c) * 512,
                            (y1c * 64 + x0c) * 512, (y1c * 64 + x1c) * 512);
        cWgt[e] = make_float4(w00, w01, w10, w11);
    }

    f32x4 acc[4][2];
#pragma unroll
    for (int df = 0; df < 4; ++df)
#pragma unroll
        for (int nf = 0; nf < 2; ++nf) acc[df][nf] = (f32x4){0.f, 0.f, 0.f, 0.f};

    const char* xc = (const char*)(xt + ((size_t)b * HW) * 256);
    const int sl = t >> 3, tj = t & 7;               // staging: w-local 0..31, sub 0..7
    const int w7 = sl & 7;

    auto stage = [&](int k, int pb) {
        const int4   co = cOff[k * 32 + sl];
        const float4 cw = cWgt[k * 32 + sl];
        ushort* Sr = &S[pb][sl * 256];
#pragma unroll
        for (int j = 0; j < 4; ++j) {
            const int oct = tj + 8 * j;
            const int cb2 = oct * 16;
            const uint4 v00 = *(const uint4*)(xc + co.x + cb2);
            const uint4 v01 = *(const uint4*)(xc + co.y + cb2);
            const uint4 v10 = *(const uint4*)(xc + co.z + cb2);
            const uint4 v11 = *(const uint4*)(xc + co.w + cb2);
            const uint a00[4] = {v00.x, v00.y, v00.z, v00.w};
            const uint a01[4] = {v01.x, v01.y, v01.z, v01.w};
            const uint a10[4] = {v10.x, v10.y, v10.z, v10.w};
            const uint a11[4] = {v11.x, v11.y, v11.z, v11.w};
            uint r[4];
#pragma unroll
            for (int q = 0; q < 4; ++q) {
                float lo = cw.x * lof(a00[q]);
                lo = fmaf(cw.y, lof(a01[q]), lo);
                lo = fmaf(cw.z, lof(a10[q]), lo);
                lo = fmaf(cw.w, lof(a11[q]), lo);
                float hi = cw.x * hif(a00[q]);
                hi = fmaf(cw.y, hif(a01[q]), hi);
                hi = fmaf(cw.z, hif(a10[q]), hi);
                hi = fmaf(cw.w, hif(a11[q]), hi);
                asm("v_cvt_pk_bf16_f32 %0, %1, %2" : "=v"(r[q]) : "v"(lo), "v"(hi));
            }
            uint4 rv = {r[0], r[1], r[2], r[3]};
            *(uint4*)(Sr + ((oct ^ w7) << 3)) = rv;
        }
    };

    auto gemm = [&](int k, int pb) {
        const ushort* A = wT + k * 65536 + (d0 + n0) * 256 + kq * 8;
#pragma unroll
        for (int c0 = 0; c0 < 256; c0 += 32) {
            short8 a[4];
#pragma unroll
            for (int df = 0; df < 4; ++df)
                a[df] = *(const short8*)(A + df * 4096 + c0);
            const int g0 = (c0 >> 3) + kq;
#pragma unroll
            for (int nf = 0; nf < 2; ++nf) {
                const int wl = nf * 16 + n0;
                const short8 bf = *(const short8*)&S[pb][wl * 256 + ((g0 ^ (wl & 7)) << 3)];
#pragma unroll
                for (int df = 0; df < 4; ++df)
                    acc[df][nf] = __builtin_amdgcn_mfma_f32_16x16x32_bf16(a[df], bf, acc[df][nf], 0, 0, 0);
            }
        }
    };

    __syncthreads();                                 // meta ready
    stage(0, 0);
    __syncthreads();
#pragma unroll 1
    for (int k = 0; k < 9; ++k) {
        if (k < 8) stage(k + 1, (k + 1) & 1);
        gemm(k, k & 1);
        __syncthreads();
    }

    float* ob = out + ((size_t)b * 256) * HW + h * 64 + wh * 32;
#pragma unroll
    for (int df = 0; df < 4; ++df)
#pragma unroll
        for (int nf = 0; nf < 2; ++nf)
#pragma unroll
            for (int r = 0; r < 4; ++r) {
                const int d = d0 + df * 16 + kq * 4 + r;
                ob[(size_t)d * HW + nf * 16 + n0] = acc[df][nf][r];
            }
}

// ---------------- k3: GroupNorm stats per (b,g) ----------------
__global__ __launch_bounds__(256) void k3_stats(const float* __restrict__ out, float* __restrict__ stats)
{
    const int bg = blockIdx.x;
    const float* p = out + (size_t)bg * 32768;
    float s = 0.f, s2 = 0.f;
    for (int i = threadIdx.x; i < 8192; i += 256) {
        float4 v = ((const float4*)p)[i];
        s  += v.x + v.y + v.z + v.w;
        s2 += v.x * v.x + v.y * v.y + v.z * v.z + v.w * v.w;
    }
    __shared__ float r1[256], r2[256];
    r1[threadIdx.x] = s; r2[threadIdx.x] = s2;
    __syncthreads();
    for (int st = 128; st > 0; st >>= 1) {
        if (threadIdx.x < st) {
            r1[threadIdx.x] += r1[threadIdx.x + st];
            r2[threadIdx.x] += r2[threadIdx.x + st];
        }
        __syncthreads();
    }
    if (threadIdx.x == 0) {
        const float mean = r1[0] / 32768.f;
        const float var  = r2[0] / 32768.f - mean * mean;
        stats[bg * 2]     = mean;
        stats[bg * 2 + 1] = rsqrtf(var + 1e-5f);
    }
}

// ---------------- k4: normalize + affine + SiLU ----------------
__global__ __launch_bounds__(256) void k4_gn(float* __restrict__ out,
    const float* __restrict__ stats, const float* __restrict__ gamma, const float* __restrict__ beta)
{
    const int i4 = blockIdx.x * 256 + threadIdx.x;
    const int elem = i4 << 2;
    const int b = elem >> 20;
    const int ch = (elem >> 12) & 255;
    const int g = ch >> 3;
    const float mean = stats[(b * 32 + g) * 2];
    const float rstd = stats[(b * 32 + g) * 2 + 1];
    const float ga = gamma[ch], be = beta[ch];
    float4 v = ((float4*)out)[i4];
    float vv[4] = {v.x, v.y, v.z, v.w};
#pragma unroll
    for (int j = 0; j < 4; ++j) {
        const float o = (vv[j] - mean) * rstd * ga + be;
        vv[j] = o / (1.f + expf(-o));
    }
    ((float4*)out)[i4] = make_float4(vv[0], vv[1], vv[2], vv[3]);
}

extern "C" void kernel_launch(void* const* d_in, const int* in_sizes, int n_in,
                              void* d_out, int out_size, void* d_ws, size_t ws_size,
                              hipStream_t stream)
{
    const float* x     = (const float*)d_in[0];
    const float* w_off = (const float*)d_in[1];
    const float* b_off = (const float*)d_in[2];
    const float* w_dcn = (const float*)d_in[3];
    const float* gamma = (const float*)d_in[4];
    const float* beta  = (const float*)d_in[5];
    float* out = (float*)d_out;

    // ws layout: xt bf16 (8 MB) | offs | mk | stats | wT bf16 | wA bf16
    ushort* xt    = (ushort*)d_ws;
    float*  offs  = (float*)d_ws + 2097152;
    float*  mk    = offs + 294912;
    float*  stats = mk + 147456;
    ushort* wT    = (ushort*)(stats + 256);
    ushort* wA    = wT + 589824;

    hipLaunchKernelGGL(k0_xt,    dim3(512),  dim3(256), 0, stream, x, xt);
    hipLaunchKernelGGL(k0_w,     dim3(544),  dim3(256), 0, stream, w_dcn, w_off, wT, wA);
    hipLaunchKernelGGL(k1_mfma,  dim3(512),  dim3(512), 0, stream, xt, wA, b_off, offs, mk);
    hipLaunchKernelGGL(k2_dcn,   dim3(512),  dim3(256), 0, stream, xt, wT, offs, mk, out);
    hipLaunchKernelGGL(k3_stats, dim3(128),  dim3(256), 0, stream, out, stats);
    hipLaunchKernelGGL(k4_gn,    dim3(4096), dim3(256), 0, stream, out, stats, gamma, beta);
}